// Round 15
// baseline (85.115 us; speedup 1.0000x reference)
//
#include <hip/hip_runtime.h>

// Problem constants (fixed by reference setup_inputs)
namespace {
constexpr int B_  = 4;
constexpr int C_  = 64;
constexpr int N_  = 16384;
constexpr int K_  = 16;
constexpr int R3_ = 4096;   // 16^3

// workspace layout (in floats)
constexpr int OFF_MEANS = 0;                         // 12 (pad 16)
constexpr int OFF_XT    = 16;                        // bf16 [B,N,C] (pre-scaled by ts)
constexpr int OFF_PTS   = OFF_XT   + B_*N_*C_/2;     // f32  [B,N,8]
constexpr int OFF_PTSH  = OFF_PTS  + B_*N_*8;        // bf16x2 [B,N,4]
constexpr int OFF_DVT   = OFF_PTSH + B_*N_*4;        // u32 [B,N,2] {base|fz, fx|fy}
constexpr int OFF_SUMS  = OFF_DVT  + B_*N_*8;        // f32  [B,R3,C]
constexpr int OFF_CNTS  = OFF_SUMS + B_*R3_*C_;      // f32  [B,R3]
constexpr int OFF_VT16  = OFF_CNTS + B_*R3_;         // bf16 [B,C,R3]
constexpr int OFF_VOX2  = OFF_VT16 + B_*C_*R3_/2;    // f32  [B,C,R3] conv2 out
constexpr int FILL_FLOATS = B_*R3_*C_ + B_*R3_;      // sums + cnts, contiguous
constexpr int FILL_BLOCKS = FILL_FLOATS / (256 * 4); // = 1040 exactly
}

__device__ __forceinline__ unsigned short f2bf(float f) {
  unsigned u = __float_as_uint(f);
  return (unsigned short)((u + 0x7FFFu + ((u >> 16) & 1u)) >> 16);   // RNE
}
__device__ __forceinline__ unsigned cvtpk_bf16(float lo, float hi) {
  unsigned r;
  asm("v_cvt_pk_bf16_f32 %0, %1, %2" : "=v"(r) : "v"(lo), "v"(hi));
  return r;
}
__device__ __forceinline__ float bflo(unsigned u) { return __uint_as_float(u << 16); }
__device__ __forceinline__ float bfhi(unsigned u) { return __uint_as_float(u & 0xffff0000u); }

// ---------------------------------------------------------------------------
// Kernel 1: blocks 0-11 -> per-(batch,axis) fp64 mean of xyz;
//           blocks 12+  -> float4 zero-fill of sums+cnts (4.26 MB).
// ---------------------------------------------------------------------------
__global__ __launch_bounds__(256) void k_init(
    const float* __restrict__ xyz, float* __restrict__ means,
    float* __restrict__ fill) {
  const int blk = blockIdx.x;
  if (blk >= 12) {
    const int base = (blk - 12) * (256 * 4) + threadIdx.x * 4;
    *(float4*)(fill + base) = make_float4(0.f, 0.f, 0.f, 0.f);
    return;
  }
  __shared__ double red[256];
  const float* p = xyz + blk * N_;
  double s = 0.0;
  for (int i = threadIdx.x; i < N_; i += 256) s += (double)p[i];
  red[threadIdx.x] = s;
  __syncthreads();
  for (int st = 128; st; st >>= 1) {
    if (threadIdx.x < st) red[threadIdx.x] += red[threadIdx.x + st];
    __syncthreads();
  }
  if (threadIdx.x == 0) means[blk] = (float)(red[0] * (1.0 / (double)N_));
}

// ---------------------------------------------------------------------------
// Kernel 2 (r14 proven): transpose x -> xT bf16 pre-scaled by ts, hproj,
// pts8 + ptsh + compact dvt, voxel scatter via global atomics.
// ---------------------------------------------------------------------------
__global__ __launch_bounds__(256) void k_prep(
    const float* __restrict__ x, const float* __restrict__ xyz,
    const float* __restrict__ pw1, const float* __restrict__ means,
    const float* __restrict__ ptbn,
    unsigned short* __restrict__ xT, float* __restrict__ pts,
    unsigned* __restrict__ ptsh, unsigned* __restrict__ dvt,
    float* __restrict__ sums, float* __restrict__ cnts) {
  __shared__ float tile[64 * 65];
  __shared__ float ncs[3][64];
  __shared__ float xys[3][64];
  __shared__ float hps[3][64];
  __shared__ float tss[64];
  __shared__ int   flats[64];

  const int t   = threadIdx.x;
  const int blk = blockIdx.x;
  const int b   = blk >> 8;
  const int n0  = (blk & 255) << 6;

  if (t < 64) tss[t] = ptbn[t] * rsqrtf(ptbn[192 + t] + 1e-5f);

#pragma unroll
  for (int i = 0; i < 4; ++i) {
    int c = i * 16 + (t >> 4);
    int j4 = (t & 15) * 4;
    float4 v = *(const float4*)&x[((size_t)(b * C_ + c)) * N_ + n0 + j4];
    tile[c * 65 + j4 + 0] = v.x;
    tile[c * 65 + j4 + 1] = v.y;
    tile[c * 65 + j4 + 2] = v.z;
    tile[c * 65 + j4 + 3] = v.w;
  }
  __syncthreads();

  unsigned* __restrict__ xT32 = (unsigned*)xT;
#pragma unroll
  for (int i = 0; i < 8; ++i) {
    int p = i * 8 + (t >> 5);
    int c2 = (t & 31) * 2;
    unsigned pk = cvtpk_bf16(tile[c2 * 65 + p] * tss[c2],
                             tile[(c2 + 1) * 65 + p] * tss[c2 + 1]);
    xT32[((size_t)(b * N_ + n0 + p)) * 32 + (t & 31)] = pk;
  }

  if (t < 192) {
    int p = t & 63, q = t >> 6;
    float s = 0.f;
#pragma unroll
    for (int c = 0; c < 64; ++c) s = fmaf(pw1[q * 64 + c], tile[c * 65 + p], s);
    size_t pb = ((size_t)(b * N_ + n0 + p)) * 8;
    pts[pb + 3 + q] = s;
    hps[q][p] = s;
    float v = xyz[((size_t)(b * 3 + q)) * N_ + n0 + p];
    pts[pb + q] = v;
    xys[q][p] = v;
    float nc = fminf(fmaxf((v - means[b * 3 + q] + 1.0f) * 8.0f, 0.0f), 15.0f);
    ncs[q][p] = nc;
  } else {
    int p = t & 63;
    size_t pb = ((size_t)(b * N_ + n0 + p)) * 8;
    pts[pb + 6] = 0.f;
    pts[pb + 7] = 0.f;
  }
  __syncthreads();

  if (t < 64) {
    const float nc0 = ncs[0][t], nc1 = ncs[1][t], nc2 = ncs[2][t];
    int vx = (int)rintf(nc0);
    int vy = (int)rintf(nc1);
    int vz = (int)rintf(nc2);
    int f = (vx * 16 + vy) * 16 + vz;
    flats[t] = f;
    atomicAdd(&cnts[b * R3_ + f], 1.0f);
    uint4 r;
    r.x = cvtpk_bf16(xys[0][t], xys[1][t]);
    r.y = cvtpk_bf16(xys[2][t], hps[0][t]);
    r.z = cvtpk_bf16(hps[1][t], hps[2][t]);
    r.w = 0u;
    *(uint4*)&ptsh[((size_t)(b * N_ + n0 + t)) * 4] = r;
    int lx = (int)nc0, ly = (int)nc1, lz = (int)nc2;
    float fx = nc0 - (float)lx, fy = nc1 - (float)ly, fz = nc2 - (float)lz;
    unsigned base = (unsigned)((lx * 16 + ly) * 16 + lz);
    unsigned w0 = base | (((unsigned)f2bf(fz)) << 16);
    unsigned w1 = cvtpk_bf16(fx, fy);
    *(uint2*)&dvt[((size_t)(b * N_ + n0 + t)) * 2] = make_uint2(w0, w1);
  }
  __syncthreads();

  const int w = t >> 6, lane = t & 63;
#pragma unroll
  for (int i = 0; i < 16; ++i) {
    int p = w * 16 + i;
    int f = flats[p];
    atomicAdd(&sums[((size_t)(b * R3_ + f)) * C_ + lane], tile[lane * 65 + p]);
  }
}

// ---------------------------------------------------------------------------
// Kernel 3 (MERGED point + tr): blocks [0,2048) run the r14 paired-point
// branch; blocks [2048,2304) run the 64x64 transpose+divide (independent
// after k_prep — overlaps with point). Shared-union LDS.
// ---------------------------------------------------------------------------
__global__ __launch_bounds__(256, 8) void k_pt_tr(
    const unsigned short* __restrict__ xT, const float* __restrict__ pts,
    const unsigned* __restrict__ ptsh, const int* __restrict__ idx,
    const float* __restrict__ pbn, const float* __restrict__ pw2,
    const float* __restrict__ ptbn, float* __restrict__ out,
    const float* __restrict__ sums, const float* __restrict__ cnts,
    unsigned* __restrict__ vT16) {
  __shared__ __align__(16) unsigned char smem[16896];
  const int t = threadIdx.x;
  const int blk = blockIdx.x;

  if (blk >= 2048) {
    // ---------------- tr body ----------------
    float* tile = (float*)smem;                 // 64*65 f32
    float* rs   = (float*)(smem + 16640);       // 64 f32
    const int bb = (blk - 2048) >> 6;
    const int v0 = ((blk - 2048) & 63) << 6;
#pragma unroll
    for (int i = 0; i < 16; ++i) {
      int r = i * 4 + (t >> 6);
      int c = t & 63;
      tile[r * 65 + c] = sums[((size_t)(bb * R3_ + v0 + r)) * C_ + c];
    }
    if (t < 64) rs[t] = 1.0f / fmaxf(cnts[bb * R3_ + v0 + t], 1.0f);
    __syncthreads();
#pragma unroll
    for (int i = 0; i < 8; ++i) {
      int d = t + i * 256;
      int c = d >> 5, vp = (d & 31) * 2;
      unsigned pk = cvtpk_bf16(tile[vp * 65 + c] * rs[vp],
                               tile[(vp + 1) * 65 + c] * rs[vp + 1]);
      vT16[((size_t)(bb * C_ + c)) * 2048 + (v0 >> 1) + (d & 31)] = pk;
    }
    return;
  }

  // ---------------- point body (r14) ----------------
  unsigned (*w6)[513] = (unsigned(*)[513])smem;           // 3*513 u32
  int*   jarr = (int*)(smem + 6156);                      // 512 int
  float* outT = (float*)(smem + 8204);                    // 64*33 f32

  const int xcd = blk & 7;
  const int b = xcd >> 1;
  const int t32 = ((blk >> 3) << 1) | (xcd & 1);
  const int n0 = t32 * 32;

  const float psc0 = pbn[0] * rsqrtf(pbn[9]  + 1e-5f);
  const float psc1 = pbn[1] * rsqrtf(pbn[10] + 1e-5f);
  const float psc2 = pbn[2] * rsqrtf(pbn[11] + 1e-5f);
  const float pof0 = pbn[3] - pbn[6] * psc0;
  const float pof1 = pbn[4] - pbn[7] * psc1;
  const float pof2 = pbn[5] - pbn[8] * psc2;
  float W2r[9];
#pragma unroll
  for (int i = 0; i < 9; ++i) W2r[i] = pw2[i];

  const float* __restrict__ ptsb = pts + (size_t)b * N_ * 8;
  const unsigned* __restrict__ ptshb = ptsh + (size_t)b * N_ * 4;

#pragma unroll
  for (int rep = 0; rep < 2; ++rep) {
    const int q = t + rep * 256;
    const int p = q >> 4;
    const int n = n0 + p;
    const int j = idx[(size_t)b * N_ * K_ + (size_t)n0 * K_ + q];
    jarr[q] = j;
    uint4 q4 = *(const uint4*)(ptshb + (size_t)j * 4);
    const float qx0 = bflo(q4.x), qx1 = bfhi(q4.x);
    const float qx2 = bflo(q4.y), qh0 = bfhi(q4.y);
    const float qh1 = bflo(q4.z), qh2 = bfhi(q4.z);
    const float* ir = ptsb + (size_t)n * 8;
    float4 pa = *(const float4*)ir;
    float4 pb = *(const float4*)(ir + 4);
    float d0 = qx0 - pa.x, d1 = qx1 - pa.y, d2 = qx2 - pa.z;
    float c0 = pof0 - psc0 * pa.w;
    float c1 = pof1 - psc1 * pb.x;
    float c2 = pof2 - psc2 * pb.y;
    float h0 = fmaxf(fmaf(qh0, psc0, c0), 0.f);
    float h1 = fmaxf(fmaf(qh1, psc1, c1), 0.f);
    float h2 = fmaxf(fmaf(qh2, psc2, c2), 0.f);
    float e0 = fmaf(W2r[0], h0, fmaf(W2r[1], h1, W2r[2] * h2));
    float e1 = fmaf(W2r[3], h0, fmaf(W2r[4], h1, W2r[5] * h2));
    float e2 = fmaf(W2r[6], h0, fmaf(W2r[7], h1, W2r[8] * h2));
    w6[0][q] = cvtpk_bf16(d0, d1);
    w6[1][q] = cvtpk_bf16(d2, e0);
    w6[2][q] = cvtpk_bf16(e1, e2);
  }
  __syncthreads();

  const int w = t >> 6, lane = t & 63;
  const int half = lane >> 5;
  const int d = lane & 31;
  const int widx = d < 10 ? 0 : d < 20 ? 1 : 2;
  const bool hi = (d >= 5 && d < 10) || (d >= 15 && d < 20) || (d >= 25);
  const unsigned shl = hi ? 0u : 16u;
  const int c0i = 2 * d, c1i = 2 * d + 1;
  const float ts0 = ptbn[c0i] * rsqrtf(ptbn[192 + c0i] + 1e-5f);
  const float ts1 = ptbn[c1i] * rsqrtf(ptbn[192 + c1i] + 1e-5f);
  const float td0 = ptbn[64 + c0i] - ptbn[128 + c0i] * ts0;
  const float td1 = ptbn[64 + c1i] - ptbn[128 + c1i] * ts1;
  const unsigned* __restrict__ xT32b =
      (const unsigned*)xT + (size_t)b * N_ * 32;

#pragma unroll
  for (int i = 0; i < 4; ++i) {
    const int p = i * 8 + w + half * 4;
    const int pq = p * 16;

    unsigned xju[16], wfu[16];
#pragma unroll
    for (int k = 0; k < 16; ++k) {
      const int j = jarr[pq + k];
      xju[k] = xT32b[(size_t)j * 32 + d];
      wfu[k] = w6[widx][pq + k];
    }

    float pm0 = -3.0e38f, pm1 = -3.0e38f;
#pragma unroll
    for (int k = 0; k < 16; ++k) {
      float wf = __uint_as_float(wfu[k] << shl);
      float x0 = __uint_as_float(xju[k] << 16);
      float x1 = __uint_as_float(xju[k] & 0xffff0000u);
      pm0 = fmaxf(pm0, x0 * wf);
      pm1 = fmaxf(pm1, x1 * wf);
    }

    outT[c0i * 33 + p] = fmaxf(pm0 + td0, 0.f);
    outT[c1i * 33 + p] = fmaxf(pm1 + td1, 0.f);
  }
  __syncthreads();

#pragma unroll
  for (int i = 0; i < 8; ++i) {
    int c = i * 8 + (t >> 5);
    int col = t & 31;
    out[((size_t)(b * C_ + c)) * N_ + n0 + col] = outT[c * 33 + col];
  }
}

// ---------------------------------------------------------------------------
// Kernel 4: depthwise conv3d x2 only. One block per (b,c), 256 threads,
// full z-column per thread. Output f32 [b][c][vox] (staged via LDS for
// coalesced store; no bf16 quantization of conv2 anymore).
// ---------------------------------------------------------------------------
__global__ __launch_bounds__(256) void k_conv(
    const unsigned* __restrict__ vT16,
    const float* __restrict__ w3d1, const float* __restrict__ b3d1,
    const float* __restrict__ bn1, const float* __restrict__ w3d2,
    const float* __restrict__ b3d2, const float* __restrict__ bn2,
    float* __restrict__ vox2) {
  __shared__ float va[18 * 18 * 20];
  __shared__ float vb[18 * 18 * 20];
  const int t = threadIdx.x;
  const int b = blockIdx.x >> 6;
  const int c = blockIdx.x & 63;

  float W1[27], W2[27];
#pragma unroll
  for (int i = 0; i < 27; ++i) { W1[i] = w3d1[c * 27 + i]; W2[i] = w3d2[c * 27 + i]; }
  const float s1 = bn1[c] / sqrtf(bn1[192 + c] + 1e-4f);
  const float d1 = (b3d1[c] - bn1[128 + c]) * s1 + bn1[64 + c];
  const float s2 = bn2[c] / sqrtf(bn2[192 + c] + 1e-4f);
  const float d2 = (b3d2[c] - bn2[128 + c]) * s2 + bn2[64 + c];

  for (int i = t; i < 18 * 18 * 20; i += 256) { va[i] = 0.f; vb[i] = 0.f; }
  const unsigned* __restrict__ vrow = vT16 + ((size_t)(b * C_ + c)) * 2048;
  __syncthreads();

#pragma unroll
  for (int i = 0; i < 8; ++i) {
    int dd = t + i * 256;
    unsigned u = vrow[dd];
    int vox0 = dd * 2;
    int z = vox0 & 15, yy = (vox0 >> 4) & 15, xx = vox0 >> 8;
    int base = ((xx + 1) * 18 + (yy + 1)) * 20 + (z + 1);
    va[base]     = bflo(u);
    va[base + 1] = bfhi(u);
  }
  __syncthreads();

  const int x = t >> 4, y = t & 15;
  float acc[16];

  // ---- conv1 ----
#pragma unroll
  for (int z = 0; z < 16; ++z) acc[z] = 0.f;
#pragma unroll
  for (int dx = 0; dx < 3; ++dx)
#pragma unroll
    for (int dy = 0; dy < 3; ++dy) {
      const float* row = &va[((x + dx) * 18 + (y + dy)) * 20];
      float wv[18];
      *(float4*)&wv[0]  = *(const float4*)&row[0];
      *(float4*)&wv[4]  = *(const float4*)&row[4];
      *(float4*)&wv[8]  = *(const float4*)&row[8];
      *(float4*)&wv[12] = *(const float4*)&row[12];
      wv[16] = row[16]; wv[17] = row[17];
      const float k0 = W1[(dx * 3 + dy) * 3 + 0];
      const float k1 = W1[(dx * 3 + dy) * 3 + 1];
      const float k2 = W1[(dx * 3 + dy) * 3 + 2];
#pragma unroll
      for (int z = 0; z < 16; ++z)
        acc[z] = fmaf(k0, wv[z], fmaf(k1, wv[z + 1], fmaf(k2, wv[z + 2], acc[z])));
    }
  {
    const int wb = ((x + 1) * 18 + (y + 1)) * 20 + 1;
#pragma unroll
    for (int z = 0; z < 16; ++z) {
      float tt = acc[z] * s1 + d1;
      vb[wb + z] = tt > 0.f ? tt : 0.1f * tt;
    }
  }
  __syncthreads();

  // ---- conv2 -> stage into va (flat [vox]) ----
#pragma unroll
  for (int z = 0; z < 16; ++z) acc[z] = 0.f;
#pragma unroll
  for (int dx = 0; dx < 3; ++dx)
#pragma unroll
    for (int dy = 0; dy < 3; ++dy) {
      const float* row = &vb[((x + dx) * 18 + (y + dy)) * 20];
      float wv[18];
      *(float4*)&wv[0]  = *(const float4*)&row[0];
      *(float4*)&wv[4]  = *(const float4*)&row[4];
      *(float4*)&wv[8]  = *(const float4*)&row[8];
      *(float4*)&wv[12] = *(const float4*)&row[12];
      wv[16] = row[16]; wv[17] = row[17];
      const float k0 = W2[(dx * 3 + dy) * 3 + 0];
      const float k1 = W2[(dx * 3 + dy) * 3 + 1];
      const float k2 = W2[(dx * 3 + dy) * 3 + 2];
#pragma unroll
      for (int z = 0; z < 16; ++z)
        acc[z] = fmaf(k0, wv[z], fmaf(k1, wv[z + 1], fmaf(k2, wv[z + 2], acc[z])));
    }
  {
    const int vbase = (x * 16 + y) * 16;
#pragma unroll
    for (int z = 0; z < 16; ++z) {
      float tt = acc[z] * s2 + d2;
      va[vbase + z] = tt > 0.f ? tt : 0.1f * tt;
    }
  }
  __syncthreads();

  // coalesced f32 store of the 4096-voxel row
  float* __restrict__ orow = vox2 + ((size_t)(b * C_ + c)) * R3_;
#pragma unroll
  for (int i = 0; i < 16; ++i) orow[t + i * 256] = va[t + i * 256];
}

// ---------------------------------------------------------------------------
// Kernel 5: devoxelize. grid = B*C*4 = 1024 blocks (4/CU -> 16 waves/CU),
// 256 threads. Each block LDS-loads its (b,c) conv row (16 KB f32), then
// lerp-devoxes a quarter of the 16384 points; out += (contiguous RMW).
// ---------------------------------------------------------------------------
__global__ __launch_bounds__(256) void k_devox(
    const float* __restrict__ vox2, const unsigned* __restrict__ dvt,
    float* __restrict__ out) {
  __shared__ float vls[4370];          // 4096 + zero pad (clamp reads)
  const int t = threadIdx.x;
  const int blk = blockIdx.x;
  const int b = blk >> 8;
  const int c = (blk >> 2) & 63;
  const int q = blk & 3;

  const float* __restrict__ vrow = vox2 + ((size_t)(b * C_ + c)) * R3_;
#pragma unroll
  for (int i = 0; i < 16; ++i) vls[t + i * 256] = vrow[t + i * 256];
  if (t < 274) vls[4096 + t] = 0.f;
  __syncthreads();

  const uint2* __restrict__ dv2 = (const uint2*)(dvt + (size_t)b * N_ * 2);
  float* __restrict__ orow = out + ((size_t)(b * C_ + c)) * N_;
  const int nb = q * 4096;
#pragma unroll 4
  for (int i = 0; i < 16; ++i) {
    const int n = nb + t + i * 256;
    uint2 r = dv2[n];
    float o = orow[n];
    const int base = (int)(r.x & 0xffffu);
    const float fz = bfhi(r.x);
    const float fx = bflo(r.y), fy = bfhi(r.y);
    const float* v0 = &vls[base];
    float a0 = v0[0],   a1 = v0[1];
    float b0 = v0[16],  b1 = v0[17];
    float c0 = v0[256], c1 = v0[257];
    float d0 = v0[272], d1 = v0[273];
    float zA = fmaf(fz, a1 - a0, a0);
    float zB = fmaf(fz, b1 - b0, b0);
    float zC = fmaf(fz, c1 - c0, c0);
    float zD = fmaf(fz, d1 - d0, d0);
    float yAB = fmaf(fy, zB - zA, zA);
    float yCD = fmaf(fy, zD - zC, zC);
    orow[n] = o + fmaf(fx, yCD - yAB, yAB);
  }
}

// ---------------------------------------------------------------------------
extern "C" void kernel_launch(void* const* d_in, const int* in_sizes, int n_in,
                              void* d_out, int out_size, void* d_ws, size_t ws_size,
                              hipStream_t stream) {
  const float* x     = (const float*)d_in[0];
  const float* xyz   = (const float*)d_in[1];
  const int*   idx   = (const int*)  d_in[2];
  const float* w3d1  = (const float*)d_in[3];
  const float* b3d1  = (const float*)d_in[4];
  const float* bn3d1 = (const float*)d_in[5];
  const float* w3d2  = (const float*)d_in[6];
  const float* b3d2  = (const float*)d_in[7];
  const float* bn3d2 = (const float*)d_in[8];
  const float* pw1   = (const float*)d_in[9];
  const float* pbn   = (const float*)d_in[10];
  const float* pw2   = (const float*)d_in[11];
  const float* ptbn  = (const float*)d_in[12];
  float* out = (float*)d_out;
  float* ws  = (float*)d_ws;

  k_init<<<dim3(12 + FILL_BLOCKS), dim3(256), 0, stream>>>(
      xyz, ws + OFF_MEANS, ws + OFF_SUMS);
  k_prep<<<dim3(B_ * N_ / 64), dim3(256), 0, stream>>>(
      x, xyz, pw1, ws + OFF_MEANS, ptbn,
      (unsigned short*)(ws + OFF_XT), ws + OFF_PTS,
      (unsigned*)(ws + OFF_PTSH), (unsigned*)(ws + OFF_DVT),
      ws + OFF_SUMS, ws + OFF_CNTS);
  k_pt_tr<<<dim3(B_ * N_ / 32 + B_ * 64), dim3(256), 0, stream>>>(
      (const unsigned short*)(ws + OFF_XT), ws + OFF_PTS,
      (const unsigned*)(ws + OFF_PTSH), idx, pbn, pw2, ptbn, out,
      ws + OFF_SUMS, ws + OFF_CNTS, (unsigned*)(ws + OFF_VT16));
  k_conv<<<dim3(B_ * C_), dim3(256), 0, stream>>>(
      (const unsigned*)(ws + OFF_VT16), w3d1, b3d1, bn3d1, w3d2, b3d2, bn3d2,
      ws + OFF_VOX2);
  k_devox<<<dim3(B_ * C_ * 4), dim3(256), 0, stream>>>(
      ws + OFF_VOX2, (const unsigned*)(ws + OFF_DVT), out);
}

// Round 16
// 80.978 us; speedup vs baseline: 1.0511x; 1.0511x over previous
//
#include <hip/hip_runtime.h>

// Problem constants (fixed by reference setup_inputs)
namespace {
constexpr int B_  = 4;
constexpr int C_  = 64;
constexpr int N_  = 16384;
constexpr int K_  = 16;
constexpr int R3_ = 4096;   // 16^3

// workspace layout (in floats)
constexpr int OFF_MEANS = 0;                         // 12 (pad 16)
constexpr int OFF_XT    = 16;                        // bf16 [B,N,C] (pre-scaled by ts)
constexpr int OFF_PTS   = OFF_XT   + B_*N_*C_/2;     // f32  [B,N,8]
constexpr int OFF_PTSH  = OFF_PTS  + B_*N_*8;        // bf16x2 [B,N,4]
constexpr int OFF_DVT   = OFF_PTSH + B_*N_*4;        // u32 [B,N,2] {base|fz, fx|fy}
constexpr int OFF_SUMS  = OFF_DVT  + B_*N_*8;        // f32  [B,R3,C]
constexpr int OFF_CNTS  = OFF_SUMS + B_*R3_*C_;      // f32  [B,R3]
constexpr int OFF_VT16  = OFF_CNTS + B_*R3_;         // bf16 [B,C,R3]
constexpr int FILL_FLOATS = B_*R3_*C_ + B_*R3_;      // sums + cnts, contiguous
constexpr int FILL_BLOCKS = FILL_FLOATS / (256 * 4); // = 1040 exactly
}

__device__ __forceinline__ unsigned short f2bf(float f) {
  unsigned u = __float_as_uint(f);
  return (unsigned short)((u + 0x7FFFu + ((u >> 16) & 1u)) >> 16);   // RNE
}
__device__ __forceinline__ unsigned cvtpk_bf16(float lo, float hi) {
  unsigned r;
  asm("v_cvt_pk_bf16_f32 %0, %1, %2" : "=v"(r) : "v"(lo), "v"(hi));
  return r;
}
__device__ __forceinline__ float bflo(unsigned u) { return __uint_as_float(u << 16); }
__device__ __forceinline__ float bfhi(unsigned u) { return __uint_as_float(u & 0xffff0000u); }

// ---------------------------------------------------------------------------
// Kernel 1: blocks 0-11 -> per-(batch,axis) fp64 mean of xyz;
//           blocks 12+  -> float4 zero-fill of sums+cnts (4.26 MB).
// ---------------------------------------------------------------------------
__global__ __launch_bounds__(256) void k_init(
    const float* __restrict__ xyz, float* __restrict__ means,
    float* __restrict__ fill) {
  const int blk = blockIdx.x;
  if (blk >= 12) {
    const int base = (blk - 12) * (256 * 4) + threadIdx.x * 4;
    *(float4*)(fill + base) = make_float4(0.f, 0.f, 0.f, 0.f);
    return;
  }
  __shared__ double red[256];
  const float* p = xyz + blk * N_;
  double s = 0.0;
  for (int i = threadIdx.x; i < N_; i += 256) s += (double)p[i];
  red[threadIdx.x] = s;
  __syncthreads();
  for (int st = 128; st; st >>= 1) {
    if (threadIdx.x < st) red[threadIdx.x] += red[threadIdx.x + st];
    __syncthreads();
  }
  if (threadIdx.x == 0) means[blk] = (float)(red[0] * (1.0 / (double)N_));
}

// ---------------------------------------------------------------------------
// Kernel 2 (r14 proven): transpose x -> xT bf16 pre-scaled by ts, hproj,
// pts8 + ptsh + compact dvt, voxel scatter via global atomics.
// ---------------------------------------------------------------------------
__global__ __launch_bounds__(256) void k_prep(
    const float* __restrict__ x, const float* __restrict__ xyz,
    const float* __restrict__ pw1, const float* __restrict__ means,
    const float* __restrict__ ptbn,
    unsigned short* __restrict__ xT, float* __restrict__ pts,
    unsigned* __restrict__ ptsh, unsigned* __restrict__ dvt,
    float* __restrict__ sums, float* __restrict__ cnts) {
  __shared__ float tile[64 * 65];
  __shared__ float ncs[3][64];
  __shared__ float xys[3][64];
  __shared__ float hps[3][64];
  __shared__ float tss[64];
  __shared__ int   flats[64];

  const int t   = threadIdx.x;
  const int blk = blockIdx.x;
  const int b   = blk >> 8;
  const int n0  = (blk & 255) << 6;

  if (t < 64) tss[t] = ptbn[t] * rsqrtf(ptbn[192 + t] + 1e-5f);

#pragma unroll
  for (int i = 0; i < 4; ++i) {
    int c = i * 16 + (t >> 4);
    int j4 = (t & 15) * 4;
    float4 v = *(const float4*)&x[((size_t)(b * C_ + c)) * N_ + n0 + j4];
    tile[c * 65 + j4 + 0] = v.x;
    tile[c * 65 + j4 + 1] = v.y;
    tile[c * 65 + j4 + 2] = v.z;
    tile[c * 65 + j4 + 3] = v.w;
  }
  __syncthreads();

  unsigned* __restrict__ xT32 = (unsigned*)xT;
#pragma unroll
  for (int i = 0; i < 8; ++i) {
    int p = i * 8 + (t >> 5);
    int c2 = (t & 31) * 2;
    unsigned pk = cvtpk_bf16(tile[c2 * 65 + p] * tss[c2],
                             tile[(c2 + 1) * 65 + p] * tss[c2 + 1]);
    xT32[((size_t)(b * N_ + n0 + p)) * 32 + (t & 31)] = pk;
  }

  if (t < 192) {
    int p = t & 63, q = t >> 6;
    float s = 0.f;
#pragma unroll
    for (int c = 0; c < 64; ++c) s = fmaf(pw1[q * 64 + c], tile[c * 65 + p], s);
    size_t pb = ((size_t)(b * N_ + n0 + p)) * 8;
    pts[pb + 3 + q] = s;
    hps[q][p] = s;
    float v = xyz[((size_t)(b * 3 + q)) * N_ + n0 + p];
    pts[pb + q] = v;
    xys[q][p] = v;
    float nc = fminf(fmaxf((v - means[b * 3 + q] + 1.0f) * 8.0f, 0.0f), 15.0f);
    ncs[q][p] = nc;
  } else {
    int p = t & 63;
    size_t pb = ((size_t)(b * N_ + n0 + p)) * 8;
    pts[pb + 6] = 0.f;
    pts[pb + 7] = 0.f;
  }
  __syncthreads();

  if (t < 64) {
    const float nc0 = ncs[0][t], nc1 = ncs[1][t], nc2 = ncs[2][t];
    int vx = (int)rintf(nc0);
    int vy = (int)rintf(nc1);
    int vz = (int)rintf(nc2);
    int f = (vx * 16 + vy) * 16 + vz;
    flats[t] = f;
    atomicAdd(&cnts[b * R3_ + f], 1.0f);
    uint4 r;
    r.x = cvtpk_bf16(xys[0][t], xys[1][t]);
    r.y = cvtpk_bf16(xys[2][t], hps[0][t]);
    r.z = cvtpk_bf16(hps[1][t], hps[2][t]);
    r.w = 0u;
    *(uint4*)&ptsh[((size_t)(b * N_ + n0 + t)) * 4] = r;
    int lx = (int)nc0, ly = (int)nc1, lz = (int)nc2;
    float fx = nc0 - (float)lx, fy = nc1 - (float)ly, fz = nc2 - (float)lz;
    unsigned base = (unsigned)((lx * 16 + ly) * 16 + lz);
    unsigned w0 = base | (((unsigned)f2bf(fz)) << 16);
    unsigned w1 = cvtpk_bf16(fx, fy);
    *(uint2*)&dvt[((size_t)(b * N_ + n0 + t)) * 2] = make_uint2(w0, w1);
  }
  __syncthreads();

  const int w = t >> 6, lane = t & 63;
#pragma unroll
  for (int i = 0; i < 16; ++i) {
    int p = w * 16 + i;
    int f = flats[p];
    atomicAdd(&sums[((size_t)(b * R3_ + f)) * C_ + lane], tile[lane * 65 + p]);
  }
}

// ---------------------------------------------------------------------------
// Kernel 3 (MERGED point + tr): blocks [0,2048) run the r14 paired-point
// branch; blocks [2048,2304) run the 64x64 transpose+divide (independent
// after k_prep — overlaps with point). Shared-union LDS.
// ---------------------------------------------------------------------------
__global__ __launch_bounds__(256, 8) void k_pt_tr(
    const unsigned short* __restrict__ xT, const float* __restrict__ pts,
    const unsigned* __restrict__ ptsh, const int* __restrict__ idx,
    const float* __restrict__ pbn, const float* __restrict__ pw2,
    const float* __restrict__ ptbn, float* __restrict__ out,
    const float* __restrict__ sums, const float* __restrict__ cnts,
    unsigned* __restrict__ vT16) {
  __shared__ __align__(16) unsigned char smem[16896];
  const int t = threadIdx.x;
  const int blk = blockIdx.x;

  if (blk >= 2048) {
    // ---------------- tr body ----------------
    float* tile = (float*)smem;                 // 64*65 f32
    float* rs   = (float*)(smem + 16640);       // 64 f32
    const int bb = (blk - 2048) >> 6;
    const int v0 = ((blk - 2048) & 63) << 6;
#pragma unroll
    for (int i = 0; i < 16; ++i) {
      int r = i * 4 + (t >> 6);
      int c = t & 63;
      tile[r * 65 + c] = sums[((size_t)(bb * R3_ + v0 + r)) * C_ + c];
    }
    if (t < 64) rs[t] = 1.0f / fmaxf(cnts[bb * R3_ + v0 + t], 1.0f);
    __syncthreads();
#pragma unroll
    for (int i = 0; i < 8; ++i) {
      int d = t + i * 256;
      int c = d >> 5, vp = (d & 31) * 2;
      unsigned pk = cvtpk_bf16(tile[vp * 65 + c] * rs[vp],
                               tile[(vp + 1) * 65 + c] * rs[vp + 1]);
      vT16[((size_t)(bb * C_ + c)) * 2048 + (v0 >> 1) + (d & 31)] = pk;
    }
    return;
  }

  // ---------------- point body (r14) ----------------
  unsigned (*w6)[513] = (unsigned(*)[513])smem;           // 3*513 u32
  int*   jarr = (int*)(smem + 6156);                      // 512 int
  float* outT = (float*)(smem + 8204);                    // 64*33 f32

  const int xcd = blk & 7;
  const int b = xcd >> 1;
  const int t32 = ((blk >> 3) << 1) | (xcd & 1);
  const int n0 = t32 * 32;

  const float psc0 = pbn[0] * rsqrtf(pbn[9]  + 1e-5f);
  const float psc1 = pbn[1] * rsqrtf(pbn[10] + 1e-5f);
  const float psc2 = pbn[2] * rsqrtf(pbn[11] + 1e-5f);
  const float pof0 = pbn[3] - pbn[6] * psc0;
  const float pof1 = pbn[4] - pbn[7] * psc1;
  const float pof2 = pbn[5] - pbn[8] * psc2;
  float W2r[9];
#pragma unroll
  for (int i = 0; i < 9; ++i) W2r[i] = pw2[i];

  const float* __restrict__ ptsb = pts + (size_t)b * N_ * 8;
  const unsigned* __restrict__ ptshb = ptsh + (size_t)b * N_ * 4;

#pragma unroll
  for (int rep = 0; rep < 2; ++rep) {
    const int q = t + rep * 256;
    const int p = q >> 4;
    const int n = n0 + p;
    const int j = idx[(size_t)b * N_ * K_ + (size_t)n0 * K_ + q];
    jarr[q] = j;
    uint4 q4 = *(const uint4*)(ptshb + (size_t)j * 4);
    const float qx0 = bflo(q4.x), qx1 = bfhi(q4.x);
    const float qx2 = bflo(q4.y), qh0 = bfhi(q4.y);
    const float qh1 = bflo(q4.z), qh2 = bfhi(q4.z);
    const float* ir = ptsb + (size_t)n * 8;
    float4 pa = *(const float4*)ir;
    float4 pb = *(const float4*)(ir + 4);
    float d0 = qx0 - pa.x, d1 = qx1 - pa.y, d2 = qx2 - pa.z;
    float c0 = pof0 - psc0 * pa.w;
    float c1 = pof1 - psc1 * pb.x;
    float c2 = pof2 - psc2 * pb.y;
    float h0 = fmaxf(fmaf(qh0, psc0, c0), 0.f);
    float h1 = fmaxf(fmaf(qh1, psc1, c1), 0.f);
    float h2 = fmaxf(fmaf(qh2, psc2, c2), 0.f);
    float e0 = fmaf(W2r[0], h0, fmaf(W2r[1], h1, W2r[2] * h2));
    float e1 = fmaf(W2r[3], h0, fmaf(W2r[4], h1, W2r[5] * h2));
    float e2 = fmaf(W2r[6], h0, fmaf(W2r[7], h1, W2r[8] * h2));
    w6[0][q] = cvtpk_bf16(d0, d1);
    w6[1][q] = cvtpk_bf16(d2, e0);
    w6[2][q] = cvtpk_bf16(e1, e2);
  }
  __syncthreads();

  const int w = t >> 6, lane = t & 63;
  const int half = lane >> 5;
  const int d = lane & 31;
  const int widx = d < 10 ? 0 : d < 20 ? 1 : 2;
  const bool hi = (d >= 5 && d < 10) || (d >= 15 && d < 20) || (d >= 25);
  const unsigned shl = hi ? 0u : 16u;
  const int c0i = 2 * d, c1i = 2 * d + 1;
  const float ts0 = ptbn[c0i] * rsqrtf(ptbn[192 + c0i] + 1e-5f);
  const float ts1 = ptbn[c1i] * rsqrtf(ptbn[192 + c1i] + 1e-5f);
  const float td0 = ptbn[64 + c0i] - ptbn[128 + c0i] * ts0;
  const float td1 = ptbn[64 + c1i] - ptbn[128 + c1i] * ts1;
  const unsigned* __restrict__ xT32b =
      (const unsigned*)xT + (size_t)b * N_ * 32;

#pragma unroll
  for (int i = 0; i < 4; ++i) {
    const int p = i * 8 + w + half * 4;
    const int pq = p * 16;

    unsigned xju[16], wfu[16];
#pragma unroll
    for (int k = 0; k < 16; ++k) {
      const int j = jarr[pq + k];
      xju[k] = xT32b[(size_t)j * 32 + d];
      wfu[k] = w6[widx][pq + k];
    }

    float pm0 = -3.0e38f, pm1 = -3.0e38f;
#pragma unroll
    for (int k = 0; k < 16; ++k) {
      float wf = __uint_as_float(wfu[k] << shl);
      float x0 = __uint_as_float(xju[k] << 16);
      float x1 = __uint_as_float(xju[k] & 0xffff0000u);
      pm0 = fmaxf(pm0, x0 * wf);
      pm1 = fmaxf(pm1, x1 * wf);
    }

    outT[c0i * 33 + p] = fmaxf(pm0 + td0, 0.f);
    outT[c1i * 33 + p] = fmaxf(pm1 + td1, 0.f);
  }
  __syncthreads();

#pragma unroll
  for (int i = 0; i < 8; ++i) {
    int c = i * 8 + (t >> 5);
    int col = t & 31;
    out[((size_t)(b * C_ + c)) * N_ + n0 + col] = outT[c * 33 + col];
  }
}

// ---------------------------------------------------------------------------
// Kernel 4 (r14 proven): fused conv + devox, 512 threads. Depthwise conv3d
// x2 (half-z-column per thread), conv2 output in LDS (padded 4370 f32),
// then trilinear devox for all 16384 points via paired LDS reads + 3-lerp
// chain from compact dvt; out += (contiguous RMW).
// ---------------------------------------------------------------------------
__global__ __launch_bounds__(512) void k_convdevox(
    const unsigned* __restrict__ vT16,
    const float* __restrict__ w3d1, const float* __restrict__ b3d1,
    const float* __restrict__ bn1, const float* __restrict__ w3d2,
    const float* __restrict__ b3d2, const float* __restrict__ bn2,
    const unsigned* __restrict__ dvt, float* __restrict__ out) {
  __shared__ float va[18 * 18 * 20];
  __shared__ float vb[18 * 18 * 20];
  __shared__ float vls[4370];          // 4096 + pad (clamp reads, weight 0)
  const int t = threadIdx.x;
  const int b = blockIdx.x >> 6;
  const int c = blockIdx.x & 63;

  float W1[27], W2[27];
#pragma unroll
  for (int i = 0; i < 27; ++i) { W1[i] = w3d1[c * 27 + i]; W2[i] = w3d2[c * 27 + i]; }
  const float s1 = bn1[c] / sqrtf(bn1[192 + c] + 1e-4f);
  const float d1 = (b3d1[c] - bn1[128 + c]) * s1 + bn1[64 + c];
  const float s2 = bn2[c] / sqrtf(bn2[192 + c] + 1e-4f);
  const float d2 = (b3d2[c] - bn2[128 + c]) * s2 + bn2[64 + c];

  for (int i = t; i < 18 * 18 * 20; i += 512) { va[i] = 0.f; vb[i] = 0.f; }
  if (t < 274) vls[4096 + t] = 0.f;
  const unsigned* __restrict__ vrow = vT16 + ((size_t)(b * C_ + c)) * 2048;
  __syncthreads();

#pragma unroll
  for (int i = 0; i < 4; ++i) {
    int d = t + i * 512;
    unsigned u = vrow[d];
    int vox0 = d * 2;
    int z = vox0 & 15, yy = (vox0 >> 4) & 15, xx = vox0 >> 8;
    int base = ((xx + 1) * 18 + (yy + 1)) * 20 + (z + 1);
    va[base]     = bflo(u);
    va[base + 1] = bfhi(u);
  }
  __syncthreads();

  const int x = t >> 5, y = (t >> 1) & 15, z0 = (t & 1) * 8;
  float acc[8];

#pragma unroll
  for (int z = 0; z < 8; ++z) acc[z] = 0.f;
#pragma unroll
  for (int dx = 0; dx < 3; ++dx)
#pragma unroll
    for (int dy = 0; dy < 3; ++dy) {
      const float* row = &va[((x + dx) * 18 + (y + dy)) * 20 + z0];
      float wv[12];
      *(float4*)&wv[0] = *(const float4*)&row[0];
      *(float4*)&wv[4] = *(const float4*)&row[4];
      *(float4*)&wv[8] = *(const float4*)&row[8];
      const float k0 = W1[(dx * 3 + dy) * 3 + 0];
      const float k1 = W1[(dx * 3 + dy) * 3 + 1];
      const float k2 = W1[(dx * 3 + dy) * 3 + 2];
#pragma unroll
      for (int z = 0; z < 8; ++z)
        acc[z] = fmaf(k0, wv[z], fmaf(k1, wv[z + 1], fmaf(k2, wv[z + 2], acc[z])));
    }
  {
    const int wb = ((x + 1) * 18 + (y + 1)) * 20 + 1 + z0;
#pragma unroll
    for (int z = 0; z < 8; ++z) {
      float tt = acc[z] * s1 + d1;
      vb[wb + z] = tt > 0.f ? tt : 0.1f * tt;
    }
  }
  __syncthreads();

#pragma unroll
  for (int z = 0; z < 8; ++z) acc[z] = 0.f;
#pragma unroll
  for (int dx = 0; dx < 3; ++dx)
#pragma unroll
    for (int dy = 0; dy < 3; ++dy) {
      const float* row = &vb[((x + dx) * 18 + (y + dy)) * 20 + z0];
      float wv[12];
      *(float4*)&wv[0] = *(const float4*)&row[0];
      *(float4*)&wv[4] = *(const float4*)&row[4];
      *(float4*)&wv[8] = *(const float4*)&row[8];
      const float k0 = W2[(dx * 3 + dy) * 3 + 0];
      const float k1 = W2[(dx * 3 + dy) * 3 + 1];
      const float k2 = W2[(dx * 3 + dy) * 3 + 2];
#pragma unroll
      for (int z = 0; z < 8; ++z)
        acc[z] = fmaf(k0, wv[z], fmaf(k1, wv[z + 1], fmaf(k2, wv[z + 2], acc[z])));
    }
  {
    const int vbase = (x * 16 + y) * 16 + z0;
#pragma unroll
    for (int z = 0; z < 8; ++z) {
      float tt = acc[z] * s2 + d2;
      vls[vbase + z] = tt > 0.f ? tt : 0.1f * tt;
    }
  }
  __syncthreads();

  const uint2* __restrict__ dv2 = (const uint2*)(dvt + (size_t)b * N_ * 2);
  float* __restrict__ orow = out + ((size_t)(b * C_ + c)) * N_;
#pragma unroll 4
  for (int i = 0; i < 32; ++i) {
    const int n = t + i * 512;
    uint2 r = dv2[n];
    float o = orow[n];
    const int base = (int)(r.x & 0xffffu);
    const float fz = bfhi(r.x);
    const float fx = bflo(r.y), fy = bfhi(r.y);
    const float* v0 = &vls[base];
    float a0 = v0[0],   a1 = v0[1];
    float b0 = v0[16],  b1 = v0[17];
    float c0 = v0[256], c1 = v0[257];
    float d0 = v0[272], d1 = v0[273];
    float zA = fmaf(fz, a1 - a0, a0);
    float zB = fmaf(fz, b1 - b0, b0);
    float zC = fmaf(fz, c1 - c0, c0);
    float zD = fmaf(fz, d1 - d0, d0);
    float yAB = fmaf(fy, zB - zA, zA);
    float yCD = fmaf(fy, zD - zC, zC);
    orow[n] = o + fmaf(fx, yCD - yAB, yAB);
  }
}

// ---------------------------------------------------------------------------
extern "C" void kernel_launch(void* const* d_in, const int* in_sizes, int n_in,
                              void* d_out, int out_size, void* d_ws, size_t ws_size,
                              hipStream_t stream) {
  const float* x     = (const float*)d_in[0];
  const float* xyz   = (const float*)d_in[1];
  const int*   idx   = (const int*)  d_in[2];
  const float* w3d1  = (const float*)d_in[3];
  const float* b3d1  = (const float*)d_in[4];
  const float* bn3d1 = (const float*)d_in[5];
  const float* w3d2  = (const float*)d_in[6];
  const float* b3d2  = (const float*)d_in[7];
  const float* bn3d2 = (const float*)d_in[8];
  const float* pw1   = (const float*)d_in[9];
  const float* pbn   = (const float*)d_in[10];
  const float* pw2   = (const float*)d_in[11];
  const float* ptbn  = (const float*)d_in[12];
  float* out = (float*)d_out;
  float* ws  = (float*)d_ws;

  k_init<<<dim3(12 + FILL_BLOCKS), dim3(256), 0, stream>>>(
      xyz, ws + OFF_MEANS, ws + OFF_SUMS);
  k_prep<<<dim3(B_ * N_ / 64), dim3(256), 0, stream>>>(
      x, xyz, pw1, ws + OFF_MEANS, ptbn,
      (unsigned short*)(ws + OFF_XT), ws + OFF_PTS,
      (unsigned*)(ws + OFF_PTSH), (unsigned*)(ws + OFF_DVT),
      ws + OFF_SUMS, ws + OFF_CNTS);
  k_pt_tr<<<dim3(B_ * N_ / 32 + B_ * 64), dim3(256), 0, stream>>>(
      (const unsigned short*)(ws + OFF_XT), ws + OFF_PTS,
      (const unsigned*)(ws + OFF_PTSH), idx, pbn, pw2, ptbn, out,
      ws + OFF_SUMS, ws + OFF_CNTS, (unsigned*)(ws + OFF_VT16));
  k_convdevox<<<dim3(B_ * C_), dim3(512), 0, stream>>>(
      (const unsigned*)(ws + OFF_VT16), w3d1, b3d1, bn3d1, w3d2, b3d2, bn3d2,
      (const unsigned*)(ws + OFF_DVT), out);
}

// Round 17
// 80.366 us; speedup vs baseline: 1.0591x; 1.0076x over previous
//
#include <hip/hip_runtime.h>

// Problem constants (fixed by reference setup_inputs)
namespace {
constexpr int B_  = 4;
constexpr int C_  = 64;
constexpr int N_  = 16384;
constexpr int K_  = 16;
constexpr int R3_ = 4096;   // 16^3

// workspace layout (in floats)
constexpr int OFF_MEANS = 0;                         // 12 (pad 16)
constexpr int OFF_XT    = 16;                        // bf16 [B,N,C] (pre-scaled by ts)
constexpr int OFF_PTS   = OFF_XT   + B_*N_*C_/2;     // f32  [B,N,8]
constexpr int OFF_PTSH  = OFF_PTS  + B_*N_*8;        // bf16x2 [B,N,4]
constexpr int OFF_DVT   = OFF_PTSH + B_*N_*4;        // u32 [B,N,2] {base|fz, fx|fy}
constexpr int OFF_SUMS  = OFF_DVT  + B_*N_*8;        // f32  [B,R3,C]
constexpr int OFF_CNTS  = OFF_SUMS + B_*R3_*C_;      // f32  [B,R3]
constexpr int OFF_VT16  = OFF_CNTS + B_*R3_;         // bf16 [B,C,R3]
constexpr int FILL_FLOATS = B_*R3_*C_ + B_*R3_;      // sums + cnts, contiguous
constexpr int FILL_BLOCKS = FILL_FLOATS / (256 * 4); // = 1040 exactly
}

__device__ __forceinline__ unsigned short f2bf(float f) {
  unsigned u = __float_as_uint(f);
  return (unsigned short)((u + 0x7FFFu + ((u >> 16) & 1u)) >> 16);   // RNE
}
__device__ __forceinline__ unsigned cvtpk_bf16(float lo, float hi) {
  unsigned r;
  asm("v_cvt_pk_bf16_f32 %0, %1, %2" : "=v"(r) : "v"(lo), "v"(hi));
  return r;
}
__device__ __forceinline__ float bflo(unsigned u) { return __uint_as_float(u << 16); }
__device__ __forceinline__ float bfhi(unsigned u) { return __uint_as_float(u & 0xffff0000u); }

// ---------------------------------------------------------------------------
// Kernel 1: blocks 0-11 -> per-(batch,axis) fp64 mean of xyz;
//           blocks 12+  -> float4 zero-fill of sums+cnts (4.26 MB).
// ---------------------------------------------------------------------------
__global__ __launch_bounds__(256) void k_init(
    const float* __restrict__ xyz, float* __restrict__ means,
    float* __restrict__ fill) {
  const int blk = blockIdx.x;
  if (blk >= 12) {
    const int base = (blk - 12) * (256 * 4) + threadIdx.x * 4;
    *(float4*)(fill + base) = make_float4(0.f, 0.f, 0.f, 0.f);
    return;
  }
  __shared__ double red[256];
  const float* p = xyz + blk * N_;
  double s = 0.0;
  for (int i = threadIdx.x; i < N_; i += 256) s += (double)p[i];
  red[threadIdx.x] = s;
  __syncthreads();
  for (int st = 128; st; st >>= 1) {
    if (threadIdx.x < st) red[threadIdx.x] += red[threadIdx.x + st];
    __syncthreads();
  }
  if (threadIdx.x == 0) means[blk] = (float)(red[0] * (1.0 / (double)N_));
}

// ---------------------------------------------------------------------------
// Kernel 2 (r14 proven): transpose x -> xT bf16 pre-scaled by ts, hproj,
// pts8 + ptsh + compact dvt, voxel scatter via global atomics.
// ---------------------------------------------------------------------------
__global__ __launch_bounds__(256) void k_prep(
    const float* __restrict__ x, const float* __restrict__ xyz,
    const float* __restrict__ pw1, const float* __restrict__ means,
    const float* __restrict__ ptbn,
    unsigned short* __restrict__ xT, float* __restrict__ pts,
    unsigned* __restrict__ ptsh, unsigned* __restrict__ dvt,
    float* __restrict__ sums, float* __restrict__ cnts) {
  __shared__ float tile[64 * 65];
  __shared__ float ncs[3][64];
  __shared__ float xys[3][64];
  __shared__ float hps[3][64];
  __shared__ float tss[64];
  __shared__ int   flats[64];

  const int t   = threadIdx.x;
  const int blk = blockIdx.x;
  const int b   = blk >> 8;
  const int n0  = (blk & 255) << 6;

  if (t < 64) tss[t] = ptbn[t] * rsqrtf(ptbn[192 + t] + 1e-5f);

#pragma unroll
  for (int i = 0; i < 4; ++i) {
    int c = i * 16 + (t >> 4);
    int j4 = (t & 15) * 4;
    float4 v = *(const float4*)&x[((size_t)(b * C_ + c)) * N_ + n0 + j4];
    tile[c * 65 + j4 + 0] = v.x;
    tile[c * 65 + j4 + 1] = v.y;
    tile[c * 65 + j4 + 2] = v.z;
    tile[c * 65 + j4 + 3] = v.w;
  }
  __syncthreads();

  unsigned* __restrict__ xT32 = (unsigned*)xT;
#pragma unroll
  for (int i = 0; i < 8; ++i) {
    int p = i * 8 + (t >> 5);
    int c2 = (t & 31) * 2;
    unsigned pk = cvtpk_bf16(tile[c2 * 65 + p] * tss[c2],
                             tile[(c2 + 1) * 65 + p] * tss[c2 + 1]);
    xT32[((size_t)(b * N_ + n0 + p)) * 32 + (t & 31)] = pk;
  }

  if (t < 192) {
    int p = t & 63, q = t >> 6;
    float s = 0.f;
#pragma unroll
    for (int c = 0; c < 64; ++c) s = fmaf(pw1[q * 64 + c], tile[c * 65 + p], s);
    size_t pb = ((size_t)(b * N_ + n0 + p)) * 8;
    pts[pb + 3 + q] = s;
    hps[q][p] = s;
    float v = xyz[((size_t)(b * 3 + q)) * N_ + n0 + p];
    pts[pb + q] = v;
    xys[q][p] = v;
    float nc = fminf(fmaxf((v - means[b * 3 + q] + 1.0f) * 8.0f, 0.0f), 15.0f);
    ncs[q][p] = nc;
  } else {
    int p = t & 63;
    size_t pb = ((size_t)(b * N_ + n0 + p)) * 8;
    pts[pb + 6] = 0.f;
    pts[pb + 7] = 0.f;
  }
  __syncthreads();

  if (t < 64) {
    const float nc0 = ncs[0][t], nc1 = ncs[1][t], nc2 = ncs[2][t];
    int vx = (int)rintf(nc0);
    int vy = (int)rintf(nc1);
    int vz = (int)rintf(nc2);
    int f = (vx * 16 + vy) * 16 + vz;
    flats[t] = f;
    atomicAdd(&cnts[b * R3_ + f], 1.0f);
    uint4 r;
    r.x = cvtpk_bf16(xys[0][t], xys[1][t]);
    r.y = cvtpk_bf16(xys[2][t], hps[0][t]);
    r.z = cvtpk_bf16(hps[1][t], hps[2][t]);
    r.w = 0u;
    *(uint4*)&ptsh[((size_t)(b * N_ + n0 + t)) * 4] = r;
    int lx = (int)nc0, ly = (int)nc1, lz = (int)nc2;
    float fx = nc0 - (float)lx, fy = nc1 - (float)ly, fz = nc2 - (float)lz;
    unsigned base = (unsigned)((lx * 16 + ly) * 16 + lz);
    unsigned w0 = base | (((unsigned)f2bf(fz)) << 16);
    unsigned w1 = cvtpk_bf16(fx, fy);
    *(uint2*)&dvt[((size_t)(b * N_ + n0 + t)) * 2] = make_uint2(w0, w1);
  }
  __syncthreads();

  const int w = t >> 6, lane = t & 63;
#pragma unroll
  for (int i = 0; i < 16; ++i) {
    int p = w * 16 + i;
    int f = flats[p];
    atomicAdd(&sums[((size_t)(b * R3_ + f)) * C_ + lane], tile[lane * 65 + p]);
  }
}

// ---------------------------------------------------------------------------
// Kernel 3 (MERGED point + tr): blocks [0,2048) run the r14 paired-point
// branch; blocks [2048,2304) run the 64x64 transpose+divide (independent
// after k_prep — overlaps with point). Shared-union LDS.
// ---------------------------------------------------------------------------
__global__ __launch_bounds__(256, 8) void k_pt_tr(
    const unsigned short* __restrict__ xT, const float* __restrict__ pts,
    const unsigned* __restrict__ ptsh, const int* __restrict__ idx,
    const float* __restrict__ pbn, const float* __restrict__ pw2,
    const float* __restrict__ ptbn, float* __restrict__ out,
    const float* __restrict__ sums, const float* __restrict__ cnts,
    unsigned* __restrict__ vT16) {
  __shared__ __align__(16) unsigned char smem[16896];
  const int t = threadIdx.x;
  const int blk = blockIdx.x;

  if (blk >= 2048) {
    // ---------------- tr body ----------------
    float* tile = (float*)smem;                 // 64*65 f32
    float* rs   = (float*)(smem + 16640);       // 64 f32
    const int bb = (blk - 2048) >> 6;
    const int v0 = ((blk - 2048) & 63) << 6;
#pragma unroll
    for (int i = 0; i < 16; ++i) {
      int r = i * 4 + (t >> 6);
      int c = t & 63;
      tile[r * 65 + c] = sums[((size_t)(bb * R3_ + v0 + r)) * C_ + c];
    }
    if (t < 64) rs[t] = 1.0f / fmaxf(cnts[bb * R3_ + v0 + t], 1.0f);
    __syncthreads();
#pragma unroll
    for (int i = 0; i < 8; ++i) {
      int d = t + i * 256;
      int c = d >> 5, vp = (d & 31) * 2;
      unsigned pk = cvtpk_bf16(tile[vp * 65 + c] * rs[vp],
                               tile[(vp + 1) * 65 + c] * rs[vp + 1]);
      vT16[((size_t)(bb * C_ + c)) * 2048 + (v0 >> 1) + (d & 31)] = pk;
    }
    return;
  }

  // ---------------- point body (r14) ----------------
  unsigned (*w6)[513] = (unsigned(*)[513])smem;           // 3*513 u32
  int*   jarr = (int*)(smem + 6156);                      // 512 int
  float* outT = (float*)(smem + 8204);                    // 64*33 f32

  const int xcd = blk & 7;
  const int b = xcd >> 1;
  const int t32 = ((blk >> 3) << 1) | (xcd & 1);
  const int n0 = t32 * 32;

  const float psc0 = pbn[0] * rsqrtf(pbn[9]  + 1e-5f);
  const float psc1 = pbn[1] * rsqrtf(pbn[10] + 1e-5f);
  const float psc2 = pbn[2] * rsqrtf(pbn[11] + 1e-5f);
  const float pof0 = pbn[3] - pbn[6] * psc0;
  const float pof1 = pbn[4] - pbn[7] * psc1;
  const float pof2 = pbn[5] - pbn[8] * psc2;
  float W2r[9];
#pragma unroll
  for (int i = 0; i < 9; ++i) W2r[i] = pw2[i];

  const float* __restrict__ ptsb = pts + (size_t)b * N_ * 8;
  const unsigned* __restrict__ ptshb = ptsh + (size_t)b * N_ * 4;

#pragma unroll
  for (int rep = 0; rep < 2; ++rep) {
    const int q = t + rep * 256;
    const int p = q >> 4;
    const int n = n0 + p;
    const int j = idx[(size_t)b * N_ * K_ + (size_t)n0 * K_ + q];
    jarr[q] = j;
    uint4 q4 = *(const uint4*)(ptshb + (size_t)j * 4);
    const float qx0 = bflo(q4.x), qx1 = bfhi(q4.x);
    const float qx2 = bflo(q4.y), qh0 = bfhi(q4.y);
    const float qh1 = bflo(q4.z), qh2 = bfhi(q4.z);
    const float* ir = ptsb + (size_t)n * 8;
    float4 pa = *(const float4*)ir;
    float4 pb = *(const float4*)(ir + 4);
    float d0 = qx0 - pa.x, d1 = qx1 - pa.y, d2 = qx2 - pa.z;
    float c0 = pof0 - psc0 * pa.w;
    float c1 = pof1 - psc1 * pb.x;
    float c2 = pof2 - psc2 * pb.y;
    float h0 = fmaxf(fmaf(qh0, psc0, c0), 0.f);
    float h1 = fmaxf(fmaf(qh1, psc1, c1), 0.f);
    float h2 = fmaxf(fmaf(qh2, psc2, c2), 0.f);
    float e0 = fmaf(W2r[0], h0, fmaf(W2r[1], h1, W2r[2] * h2));
    float e1 = fmaf(W2r[3], h0, fmaf(W2r[4], h1, W2r[5] * h2));
    float e2 = fmaf(W2r[6], h0, fmaf(W2r[7], h1, W2r[8] * h2));
    w6[0][q] = cvtpk_bf16(d0, d1);
    w6[1][q] = cvtpk_bf16(d2, e0);
    w6[2][q] = cvtpk_bf16(e1, e2);
  }
  __syncthreads();

  const int w = t >> 6, lane = t & 63;
  const int half = lane >> 5;
  const int d = lane & 31;
  const int widx = d < 10 ? 0 : d < 20 ? 1 : 2;
  const bool hi = (d >= 5 && d < 10) || (d >= 15 && d < 20) || (d >= 25);
  const unsigned shl = hi ? 0u : 16u;
  const int c0i = 2 * d, c1i = 2 * d + 1;
  const float ts0 = ptbn[c0i] * rsqrtf(ptbn[192 + c0i] + 1e-5f);
  const float ts1 = ptbn[c1i] * rsqrtf(ptbn[192 + c1i] + 1e-5f);
  const float td0 = ptbn[64 + c0i] - ptbn[128 + c0i] * ts0;
  const float td1 = ptbn[64 + c1i] - ptbn[128 + c1i] * ts1;
  const unsigned* __restrict__ xT32b =
      (const unsigned*)xT + (size_t)b * N_ * 32;

#pragma unroll
  for (int i = 0; i < 4; ++i) {
    const int p = i * 8 + w + half * 4;
    const int pq = p * 16;

    unsigned xju[16], wfu[16];
#pragma unroll
    for (int k = 0; k < 16; ++k) {
      const int j = jarr[pq + k];
      xju[k] = xT32b[(size_t)j * 32 + d];
      wfu[k] = w6[widx][pq + k];
    }

    float pm0 = -3.0e38f, pm1 = -3.0e38f;
#pragma unroll
    for (int k = 0; k < 16; ++k) {
      float wf = __uint_as_float(wfu[k] << shl);
      float x0 = __uint_as_float(xju[k] << 16);
      float x1 = __uint_as_float(xju[k] & 0xffff0000u);
      pm0 = fmaxf(pm0, x0 * wf);
      pm1 = fmaxf(pm1, x1 * wf);
    }

    outT[c0i * 33 + p] = fmaxf(pm0 + td0, 0.f);
    outT[c1i * 33 + p] = fmaxf(pm1 + td1, 0.f);
  }
  __syncthreads();

#pragma unroll
  for (int i = 0; i < 8; ++i) {
    int c = i * 8 + (t >> 5);
    int col = t & 31;
    out[((size_t)(b * C_ + c)) * N_ + n0 + col] = outT[c * 33 + col];
  }
}

// ---------------------------------------------------------------------------
// Kernel 4: fused conv + devox, 1024 threads (16 waves/CU — grid is 256
// blocks on 256 CUs, so wider blocks are the only way to raise waves/CU).
// Conv runs on threads 0-511 (identical half-z-column math to r14; extra
// waves wait at barriers — no pipe contention). Fill + devox use all 1024
// threads: 2x wave-parallelism for the latency-bound scattered-LDS devox.
// ---------------------------------------------------------------------------
__global__ __launch_bounds__(1024) void k_convdevox(
    const unsigned* __restrict__ vT16,
    const float* __restrict__ w3d1, const float* __restrict__ b3d1,
    const float* __restrict__ bn1, const float* __restrict__ w3d2,
    const float* __restrict__ b3d2, const float* __restrict__ bn2,
    const unsigned* __restrict__ dvt, float* __restrict__ out) {
  __shared__ float va[18 * 18 * 20];
  __shared__ float vb[18 * 18 * 20];
  __shared__ float vls[4370];          // 4096 + pad (clamp reads, weight 0)
  const int t = threadIdx.x;
  const int b = blockIdx.x >> 6;
  const int c = blockIdx.x & 63;

  float W1[27], W2[27];
#pragma unroll
  for (int i = 0; i < 27; ++i) { W1[i] = w3d1[c * 27 + i]; W2[i] = w3d2[c * 27 + i]; }
  const float s1 = bn1[c] / sqrtf(bn1[192 + c] + 1e-4f);
  const float d1 = (b3d1[c] - bn1[128 + c]) * s1 + bn1[64 + c];
  const float s2 = bn2[c] / sqrtf(bn2[192 + c] + 1e-4f);
  const float d2 = (b3d2[c] - bn2[128 + c]) * s2 + bn2[64 + c];

  for (int i = t; i < 18 * 18 * 20; i += 1024) { va[i] = 0.f; vb[i] = 0.f; }
  if (t < 274) vls[4096 + t] = 0.f;
  const unsigned* __restrict__ vrow = vT16 + ((size_t)(b * C_ + c)) * 2048;
  __syncthreads();

  // fill va interior: 2048 dwords across 1024 threads
#pragma unroll
  for (int i = 0; i < 2; ++i) {
    int dd = t + i * 1024;
    unsigned u = vrow[dd];
    int vox0 = dd * 2;
    int z = vox0 & 15, yy = (vox0 >> 4) & 15, xx = vox0 >> 8;
    int base = ((xx + 1) * 18 + (yy + 1)) * 20 + (z + 1);
    va[base]     = bflo(u);
    va[base + 1] = bfhi(u);
  }
  __syncthreads();

  const int x = t >> 5, y = (t >> 1) & 15, z0 = (t & 1) * 8;
  float acc[8];

  if (t < 512) {
    // ---- conv1 (half z-column per thread; identical to r14) ----
#pragma unroll
    for (int z = 0; z < 8; ++z) acc[z] = 0.f;
#pragma unroll
    for (int dx = 0; dx < 3; ++dx)
#pragma unroll
      for (int dy = 0; dy < 3; ++dy) {
        const float* row = &va[((x + dx) * 18 + (y + dy)) * 20 + z0];
        float wv[12];
        *(float4*)&wv[0] = *(const float4*)&row[0];
        *(float4*)&wv[4] = *(const float4*)&row[4];
        *(float4*)&wv[8] = *(const float4*)&row[8];
        const float k0 = W1[(dx * 3 + dy) * 3 + 0];
        const float k1 = W1[(dx * 3 + dy) * 3 + 1];
        const float k2 = W1[(dx * 3 + dy) * 3 + 2];
#pragma unroll
        for (int z = 0; z < 8; ++z)
          acc[z] = fmaf(k0, wv[z], fmaf(k1, wv[z + 1], fmaf(k2, wv[z + 2], acc[z])));
      }
    const int wb = ((x + 1) * 18 + (y + 1)) * 20 + 1 + z0;
#pragma unroll
    for (int z = 0; z < 8; ++z) {
      float tt = acc[z] * s1 + d1;
      vb[wb + z] = tt > 0.f ? tt : 0.1f * tt;
    }
  }
  __syncthreads();

  if (t < 512) {
    // ---- conv2 -> vls (LDS, f32) ----
#pragma unroll
    for (int z = 0; z < 8; ++z) acc[z] = 0.f;
#pragma unroll
    for (int dx = 0; dx < 3; ++dx)
#pragma unroll
      for (int dy = 0; dy < 3; ++dy) {
        const float* row = &vb[((x + dx) * 18 + (y + dy)) * 20 + z0];
        float wv[12];
        *(float4*)&wv[0] = *(const float4*)&row[0];
        *(float4*)&wv[4] = *(const float4*)&row[4];
        *(float4*)&wv[8] = *(const float4*)&row[8];
        const float k0 = W2[(dx * 3 + dy) * 3 + 0];
        const float k1 = W2[(dx * 3 + dy) * 3 + 1];
        const float k2 = W2[(dx * 3 + dy) * 3 + 2];
#pragma unroll
        for (int z = 0; z < 8; ++z)
          acc[z] = fmaf(k0, wv[z], fmaf(k1, wv[z + 1], fmaf(k2, wv[z + 2], acc[z])));
      }
    const int vbase = (x * 16 + y) * 16 + z0;
#pragma unroll
    for (int z = 0; z < 8; ++z) {
      float tt = acc[z] * s2 + d2;
      vls[vbase + z] = tt > 0.f ? tt : 0.1f * tt;
    }
  }
  __syncthreads();

  // ---- devoxelize all N points from LDS, 16 waves active; out += ----
  const uint2* __restrict__ dv2 = (const uint2*)(dvt + (size_t)b * N_ * 2);
  float* __restrict__ orow = out + ((size_t)(b * C_ + c)) * N_;
#pragma unroll 4
  for (int i = 0; i < 16; ++i) {
    const int n = t + i * 1024;
    uint2 r = dv2[n];
    float o = orow[n];
    const int base = (int)(r.x & 0xffffu);
    const float fz = bfhi(r.x);
    const float fx = bflo(r.y), fy = bfhi(r.y);
    const float* v0 = &vls[base];
    float a0 = v0[0],   a1 = v0[1];
    float b0 = v0[16],  b1 = v0[17];
    float c0 = v0[256], c1 = v0[257];
    float d0 = v0[272], d1 = v0[273];
    float zA = fmaf(fz, a1 - a0, a0);
    float zB = fmaf(fz, b1 - b0, b0);
    float zC = fmaf(fz, c1 - c0, c0);
    float zD = fmaf(fz, d1 - d0, d0);
    float yAB = fmaf(fy, zB - zA, zA);
    float yCD = fmaf(fy, zD - zC, zC);
    orow[n] = o + fmaf(fx, yCD - yAB, yAB);
  }
}

// ---------------------------------------------------------------------------
extern "C" void kernel_launch(void* const* d_in, const int* in_sizes, int n_in,
                              void* d_out, int out_size, void* d_ws, size_t ws_size,
                              hipStream_t stream) {
  const float* x     = (const float*)d_in[0];
  const float* xyz   = (const float*)d_in[1];
  const int*   idx   = (const int*)  d_in[2];
  const float* w3d1  = (const float*)d_in[3];
  const float* b3d1  = (const float*)d_in[4];
  const float* bn3d1 = (const float*)d_in[5];
  const float* w3d2  = (const float*)d_in[6];
  const float* b3d2  = (const float*)d_in[7];
  const float* bn3d2 = (const float*)d_in[8];
  const float* pw1   = (const float*)d_in[9];
  const float* pbn   = (const float*)d_in[10];
  const float* pw2   = (const float*)d_in[11];
  const float* ptbn  = (const float*)d_in[12];
  float* out = (float*)d_out;
  float* ws  = (float*)d_ws;

  k_init<<<dim3(12 + FILL_BLOCKS), dim3(256), 0, stream>>>(
      xyz, ws + OFF_MEANS, ws + OFF_SUMS);
  k_prep<<<dim3(B_ * N_ / 64), dim3(256), 0, stream>>>(
      x, xyz, pw1, ws + OFF_MEANS, ptbn,
      (unsigned short*)(ws + OFF_XT), ws + OFF_PTS,
      (unsigned*)(ws + OFF_PTSH), (unsigned*)(ws + OFF_DVT),
      ws + OFF_SUMS, ws + OFF_CNTS);
  k_pt_tr<<<dim3(B_ * N_ / 32 + B_ * 64), dim3(256), 0, stream>>>(
      (const unsigned short*)(ws + OFF_XT), ws + OFF_PTS,
      (const unsigned*)(ws + OFF_PTSH), idx, pbn, pw2, ptbn, out,
      ws + OFF_SUMS, ws + OFF_CNTS, (unsigned*)(ws + OFF_VT16));
  k_convdevox<<<dim3(B_ * C_), dim3(1024), 0, stream>>>(
      (const unsigned*)(ws + OFF_VT16), w3d1, b3d1, bn3d1, w3d2, b3d2, bn3d2,
      (const unsigned*)(ws + OFF_DVT), out);
}

// Round 19
// 80.123 us; speedup vs baseline: 1.0623x; 1.0030x over previous
//
#include <hip/hip_runtime.h>

// Problem constants (fixed by reference setup_inputs)
namespace {
constexpr int B_  = 4;
constexpr int C_  = 64;
constexpr int N_  = 16384;
constexpr int K_  = 16;
constexpr int R3_ = 4096;   // 16^3

// workspace layout (in floats)
constexpr int OFF_MEANS = 0;                         // 12 (pad 16)
constexpr int OFF_XT    = 16;                        // bf16 [B,N,C] (pre-scaled by ts)
constexpr int OFF_PTS   = OFF_XT   + B_*N_*C_/2;     // f32  [B,N,8]
constexpr int OFF_PTSH  = OFF_PTS  + B_*N_*8;        // bf16x2 [B,N,4]
constexpr int OFF_DVT   = OFF_PTSH + B_*N_*4;        // u32 [B,N,2] {base|fz, fx|fy}
constexpr int OFF_SUMS  = OFF_DVT  + B_*N_*8;        // f32  [B,R3,C]
constexpr int OFF_CNTS  = OFF_SUMS + B_*R3_*C_;      // f32  [B,R3]
constexpr int OFF_VT16  = OFF_CNTS + B_*R3_;         // bf16 [B,C,R3]
constexpr int FILL_FLOATS = B_*R3_*C_ + B_*R3_;      // sums + cnts, contiguous
constexpr int FILL_BLOCKS = FILL_FLOATS / (256 * 4); // = 1040 exactly
}

__device__ __forceinline__ unsigned short f2bf(float f) {
  unsigned u = __float_as_uint(f);
  return (unsigned short)((u + 0x7FFFu + ((u >> 16) & 1u)) >> 16);   // RNE
}
__device__ __forceinline__ unsigned cvtpk_bf16(float lo, float hi) {
  unsigned r;
  asm("v_cvt_pk_bf16_f32 %0, %1, %2" : "=v"(r) : "v"(lo), "v"(hi));
  return r;
}
__device__ __forceinline__ float bflo(unsigned u) { return __uint_as_float(u << 16); }
__device__ __forceinline__ float bfhi(unsigned u) { return __uint_as_float(u & 0xffff0000u); }

// ---------------------------------------------------------------------------
// Kernel 1: blocks 0-11 -> per-(batch,axis) fp64 mean of xyz;
//           blocks 12+  -> float4 zero-fill of sums+cnts (4.26 MB).
// ---------------------------------------------------------------------------
__global__ __launch_bounds__(256) void k_init(
    const float* __restrict__ xyz, float* __restrict__ means,
    float* __restrict__ fill) {
  const int blk = blockIdx.x;
  if (blk >= 12) {
    const int base = (blk - 12) * (256 * 4) + threadIdx.x * 4;
    *(float4*)(fill + base) = make_float4(0.f, 0.f, 0.f, 0.f);
    return;
  }
  __shared__ double red[256];
  const float* p = xyz + blk * N_;
  double s = 0.0;
  for (int i = threadIdx.x; i < N_; i += 256) s += (double)p[i];
  red[threadIdx.x] = s;
  __syncthreads();
  for (int st = 128; st; st >>= 1) {
    if (threadIdx.x < st) red[threadIdx.x] += red[threadIdx.x + st];
    __syncthreads();
  }
  if (threadIdx.x == 0) means[blk] = (float)(red[0] * (1.0 / (double)N_));
}

// ---------------------------------------------------------------------------
// Kernel 2 (r14 proven): transpose x -> xT bf16 pre-scaled by ts, hproj,
// pts8 + ptsh + compact dvt, voxel scatter via global atomics.
// ---------------------------------------------------------------------------
__global__ __launch_bounds__(256) void k_prep(
    const float* __restrict__ x, const float* __restrict__ xyz,
    const float* __restrict__ pw1, const float* __restrict__ means,
    const float* __restrict__ ptbn,
    unsigned short* __restrict__ xT, float* __restrict__ pts,
    unsigned* __restrict__ ptsh, unsigned* __restrict__ dvt,
    float* __restrict__ sums, float* __restrict__ cnts) {
  __shared__ float tile[64 * 65];
  __shared__ float ncs[3][64];
  __shared__ float xys[3][64];
  __shared__ float hps[3][64];
  __shared__ float tss[64];
  __shared__ int   flats[64];

  const int t   = threadIdx.x;
  const int blk = blockIdx.x;
  const int b   = blk >> 8;
  const int n0  = (blk & 255) << 6;

  if (t < 64) tss[t] = ptbn[t] * rsqrtf(ptbn[192 + t] + 1e-5f);

#pragma unroll
  for (int i = 0; i < 4; ++i) {
    int c = i * 16 + (t >> 4);
    int j4 = (t & 15) * 4;
    float4 v = *(const float4*)&x[((size_t)(b * C_ + c)) * N_ + n0 + j4];
    tile[c * 65 + j4 + 0] = v.x;
    tile[c * 65 + j4 + 1] = v.y;
    tile[c * 65 + j4 + 2] = v.z;
    tile[c * 65 + j4 + 3] = v.w;
  }
  __syncthreads();

  unsigned* __restrict__ xT32 = (unsigned*)xT;
#pragma unroll
  for (int i = 0; i < 8; ++i) {
    int p = i * 8 + (t >> 5);
    int c2 = (t & 31) * 2;
    unsigned pk = cvtpk_bf16(tile[c2 * 65 + p] * tss[c2],
                             tile[(c2 + 1) * 65 + p] * tss[c2 + 1]);
    xT32[((size_t)(b * N_ + n0 + p)) * 32 + (t & 31)] = pk;
  }

  if (t < 192) {
    int p = t & 63, q = t >> 6;
    float s = 0.f;
#pragma unroll
    for (int c = 0; c < 64; ++c) s = fmaf(pw1[q * 64 + c], tile[c * 65 + p], s);
    size_t pb = ((size_t)(b * N_ + n0 + p)) * 8;
    pts[pb + 3 + q] = s;
    hps[q][p] = s;
    float v = xyz[((size_t)(b * 3 + q)) * N_ + n0 + p];
    pts[pb + q] = v;
    xys[q][p] = v;
    float nc = fminf(fmaxf((v - means[b * 3 + q] + 1.0f) * 8.0f, 0.0f), 15.0f);
    ncs[q][p] = nc;
  } else {
    int p = t & 63;
    size_t pb = ((size_t)(b * N_ + n0 + p)) * 8;
    pts[pb + 6] = 0.f;
    pts[pb + 7] = 0.f;
  }
  __syncthreads();

  if (t < 64) {
    const float nc0 = ncs[0][t], nc1 = ncs[1][t], nc2 = ncs[2][t];
    int vx = (int)rintf(nc0);
    int vy = (int)rintf(nc1);
    int vz = (int)rintf(nc2);
    int f = (vx * 16 + vy) * 16 + vz;
    flats[t] = f;
    atomicAdd(&cnts[b * R3_ + f], 1.0f);
    uint4 r;
    r.x = cvtpk_bf16(xys[0][t], xys[1][t]);
    r.y = cvtpk_bf16(xys[2][t], hps[0][t]);
    r.z = cvtpk_bf16(hps[1][t], hps[2][t]);
    r.w = 0u;
    *(uint4*)&ptsh[((size_t)(b * N_ + n0 + t)) * 4] = r;
    int lx = (int)nc0, ly = (int)nc1, lz = (int)nc2;
    float fx = nc0 - (float)lx, fy = nc1 - (float)ly, fz = nc2 - (float)lz;
    unsigned base = (unsigned)((lx * 16 + ly) * 16 + lz);
    unsigned w0 = base | (((unsigned)f2bf(fz)) << 16);
    unsigned w1 = cvtpk_bf16(fx, fy);
    *(uint2*)&dvt[((size_t)(b * N_ + n0 + t)) * 2] = make_uint2(w0, w1);
  }
  __syncthreads();

  const int w = t >> 6, lane = t & 63;
#pragma unroll
  for (int i = 0; i < 16; ++i) {
    int p = w * 16 + i;
    int f = flats[p];
    atomicAdd(&sums[((size_t)(b * R3_ + f)) * C_ + lane], tile[lane * 65 + p]);
  }
}

// ---------------------------------------------------------------------------
// Kernel 3 (MERGED point + tr): blocks [0,2048) run the r14 paired-point
// branch; blocks [2048,2304) run the 64x64 transpose+divide (independent
// after k_prep — overlaps with point). Shared-union LDS.
// ---------------------------------------------------------------------------
__global__ __launch_bounds__(256, 8) void k_pt_tr(
    const unsigned short* __restrict__ xT, const float* __restrict__ pts,
    const unsigned* __restrict__ ptsh, const int* __restrict__ idx,
    const float* __restrict__ pbn, const float* __restrict__ pw2,
    const float* __restrict__ ptbn, float* __restrict__ out,
    const float* __restrict__ sums, const float* __restrict__ cnts,
    unsigned* __restrict__ vT16) {
  __shared__ __align__(16) unsigned char smem[16896];
  const int t = threadIdx.x;
  const int blk = blockIdx.x;

  if (blk >= 2048) {
    // ---------------- tr body ----------------
    float* tile = (float*)smem;                 // 64*65 f32
    float* rs   = (float*)(smem + 16640);       // 64 f32
    const int bb = (blk - 2048) >> 6;
    const int v0 = ((blk - 2048) & 63) << 6;
#pragma unroll
    for (int i = 0; i < 16; ++i) {
      int r = i * 4 + (t >> 6);
      int c = t & 63;
      tile[r * 65 + c] = sums[((size_t)(bb * R3_ + v0 + r)) * C_ + c];
    }
    if (t < 64) rs[t] = 1.0f / fmaxf(cnts[bb * R3_ + v0 + t], 1.0f);
    __syncthreads();
#pragma unroll
    for (int i = 0; i < 8; ++i) {
      int d = t + i * 256;
      int c = d >> 5, vp = (d & 31) * 2;
      unsigned pk = cvtpk_bf16(tile[vp * 65 + c] * rs[vp],
                               tile[(vp + 1) * 65 + c] * rs[vp + 1]);
      vT16[((size_t)(bb * C_ + c)) * 2048 + (v0 >> 1) + (d & 31)] = pk;
    }
    return;
  }

  // ---------------- point body (r14) ----------------
  unsigned (*w6)[513] = (unsigned(*)[513])smem;           // 3*513 u32
  int*   jarr = (int*)(smem + 6156);                      // 512 int
  float* outT = (float*)(smem + 8204);                    // 64*33 f32

  const int xcd = blk & 7;
  const int b = xcd >> 1;
  const int t32 = ((blk >> 3) << 1) | (xcd & 1);
  const int n0 = t32 * 32;

  const float psc0 = pbn[0] * rsqrtf(pbn[9]  + 1e-5f);
  const float psc1 = pbn[1] * rsqrtf(pbn[10] + 1e-5f);
  const float psc2 = pbn[2] * rsqrtf(pbn[11] + 1e-5f);
  const float pof0 = pbn[3] - pbn[6] * psc0;
  const float pof1 = pbn[4] - pbn[7] * psc1;
  const float pof2 = pbn[5] - pbn[8] * psc2;
  float W2r[9];
#pragma unroll
  for (int i = 0; i < 9; ++i) W2r[i] = pw2[i];

  const float* __restrict__ ptsb = pts + (size_t)b * N_ * 8;
  const unsigned* __restrict__ ptshb = ptsh + (size_t)b * N_ * 4;

#pragma unroll
  for (int rep = 0; rep < 2; ++rep) {
    const int q = t + rep * 256;
    const int p = q >> 4;
    const int n = n0 + p;
    const int j = idx[(size_t)b * N_ * K_ + (size_t)n0 * K_ + q];
    jarr[q] = j;
    uint4 q4 = *(const uint4*)(ptshb + (size_t)j * 4);
    const float qx0 = bflo(q4.x), qx1 = bfhi(q4.x);
    const float qx2 = bflo(q4.y), qh0 = bfhi(q4.y);
    const float qh1 = bflo(q4.z), qh2 = bfhi(q4.z);
    const float* ir = ptsb + (size_t)n * 8;
    float4 pa = *(const float4*)ir;
    float4 pb = *(const float4*)(ir + 4);
    float d0 = qx0 - pa.x, d1 = qx1 - pa.y, d2 = qx2 - pa.z;
    float c0 = pof0 - psc0 * pa.w;
    float c1 = pof1 - psc1 * pb.x;
    float c2 = pof2 - psc2 * pb.y;
    float h0 = fmaxf(fmaf(qh0, psc0, c0), 0.f);
    float h1 = fmaxf(fmaf(qh1, psc1, c1), 0.f);
    float h2 = fmaxf(fmaf(qh2, psc2, c2), 0.f);
    float e0 = fmaf(W2r[0], h0, fmaf(W2r[1], h1, W2r[2] * h2));
    float e1 = fmaf(W2r[3], h0, fmaf(W2r[4], h1, W2r[5] * h2));
    float e2 = fmaf(W2r[6], h0, fmaf(W2r[7], h1, W2r[8] * h2));
    w6[0][q] = cvtpk_bf16(d0, d1);
    w6[1][q] = cvtpk_bf16(d2, e0);
    w6[2][q] = cvtpk_bf16(e1, e2);
  }
  __syncthreads();

  const int w = t >> 6, lane = t & 63;
  const int half = lane >> 5;
  const int d = lane & 31;
  const int widx = d < 10 ? 0 : d < 20 ? 1 : 2;
  const bool hi = (d >= 5 && d < 10) || (d >= 15 && d < 20) || (d >= 25);
  const unsigned shl = hi ? 0u : 16u;
  const int c0i = 2 * d, c1i = 2 * d + 1;
  const float ts0 = ptbn[c0i] * rsqrtf(ptbn[192 + c0i] + 1e-5f);
  const float ts1 = ptbn[c1i] * rsqrtf(ptbn[192 + c1i] + 1e-5f);
  const float td0 = ptbn[64 + c0i] - ptbn[128 + c0i] * ts0;
  const float td1 = ptbn[64 + c1i] - ptbn[128 + c1i] * ts1;
  const unsigned* __restrict__ xT32b =
      (const unsigned*)xT + (size_t)b * N_ * 32;

#pragma unroll
  for (int i = 0; i < 4; ++i) {
    const int p = i * 8 + w + half * 4;
    const int pq = p * 16;

    unsigned xju[16], wfu[16];
#pragma unroll
    for (int k = 0; k < 16; ++k) {
      const int j = jarr[pq + k];
      xju[k] = xT32b[(size_t)j * 32 + d];
      wfu[k] = w6[widx][pq + k];
    }

    float pm0 = -3.0e38f, pm1 = -3.0e38f;
#pragma unroll
    for (int k = 0; k < 16; ++k) {
      float wf = __uint_as_float(wfu[k] << shl);
      float x0 = __uint_as_float(xju[k] << 16);
      float x1 = __uint_as_float(xju[k] & 0xffff0000u);
      pm0 = fmaxf(pm0, x0 * wf);
      pm1 = fmaxf(pm1, x1 * wf);
    }

    outT[c0i * 33 + p] = fmaxf(pm0 + td0, 0.f);
    outT[c1i * 33 + p] = fmaxf(pm1 + td1, 0.f);
  }
  __syncthreads();

#pragma unroll
  for (int i = 0; i < 8; ++i) {
    int c = i * 8 + (t >> 5);
    int col = t & 31;
    out[((size_t)(b * C_ + c)) * N_ + n0 + col] = outT[c * 33 + col];
  }
}

// ---------------------------------------------------------------------------
// Kernel 4: fused conv + devox, 1024 threads (16 waves/CU). Conv on threads
// 0-511 (half-z-column each); fill + devox on all 1024 threads.
// ---------------------------------------------------------------------------
__global__ __launch_bounds__(1024) void k_convdevox(
    const unsigned* __restrict__ vT16,
    const float* __restrict__ w3d1, const float* __restrict__ b3d1,
    const float* __restrict__ bn1, const float* __restrict__ w3d2,
    const float* __restrict__ b3d2, const float* __restrict__ bn2,
    const unsigned* __restrict__ dvt, float* __restrict__ out) {
  __shared__ float va[18 * 18 * 20];
  __shared__ float vb[18 * 18 * 20];
  __shared__ float vls[4370];          // 4096 + pad (clamp reads, weight 0)
  const int t = threadIdx.x;
  const int b = blockIdx.x >> 6;
  const int c = blockIdx.x & 63;

  float W1[27], W2[27];
#pragma unroll
  for (int i = 0; i < 27; ++i) { W1[i] = w3d1[c * 27 + i]; W2[i] = w3d2[c * 27 + i]; }
  const float s1 = bn1[c] / sqrtf(bn1[192 + c] + 1e-4f);
  const float d1 = (b3d1[c] - bn1[128 + c]) * s1 + bn1[64 + c];
  const float s2 = bn2[c] / sqrtf(bn2[192 + c] + 1e-4f);
  const float d2 = (b3d2[c] - bn2[128 + c]) * s2 + bn2[64 + c];

  for (int i = t; i < 18 * 18 * 20; i += 1024) { va[i] = 0.f; vb[i] = 0.f; }
  if (t < 274) vls[4096 + t] = 0.f;
  const unsigned* __restrict__ vrow = vT16 + ((size_t)(b * C_ + c)) * 2048;
  __syncthreads();

#pragma unroll
  for (int i = 0; i < 2; ++i) {
    int dd = t + i * 1024;
    unsigned u = vrow[dd];
    int vox0 = dd * 2;
    int z = vox0 & 15, yy = (vox0 >> 4) & 15, xx = vox0 >> 8;
    int base = ((xx + 1) * 18 + (yy + 1)) * 20 + (z + 1);
    va[base]     = bflo(u);
    va[base + 1] = bfhi(u);
  }
  __syncthreads();

  const int x = t >> 5, y = (t >> 1) & 15, z0 = (t & 1) * 8;
  float acc[8];

  if (t < 512) {
#pragma unroll
    for (int z = 0; z < 8; ++z) acc[z] = 0.f;
#pragma unroll
    for (int dx = 0; dx < 3; ++dx)
#pragma unroll
      for (int dy = 0; dy < 3; ++dy) {
        const float* row = &va[((x + dx) * 18 + (y + dy)) * 20 + z0];
        float wv[12];
        *(float4*)&wv[0] = *(const float4*)&row[0];
        *(float4*)&wv[4] = *(const float4*)&row[4];
        *(float4*)&wv[8] = *(const float4*)&row[8];
        const float k0 = W1[(dx * 3 + dy) * 3 + 0];
        const float k1 = W1[(dx * 3 + dy) * 3 + 1];
        const float k2 = W1[(dx * 3 + dy) * 3 + 2];
#pragma unroll
        for (int z = 0; z < 8; ++z)
          acc[z] = fmaf(k0, wv[z], fmaf(k1, wv[z + 1], fmaf(k2, wv[z + 2], acc[z])));
      }
    const int wb = ((x + 1) * 18 + (y + 1)) * 20 + 1 + z0;
#pragma unroll
    for (int z = 0; z < 8; ++z) {
      float tt = acc[z] * s1 + d1;
      vb[wb + z] = tt > 0.f ? tt : 0.1f * tt;
    }
  }
  __syncthreads();

  if (t < 512) {
#pragma unroll
    for (int z = 0; z < 8; ++z) acc[z] = 0.f;
#pragma unroll
    for (int dx = 0; dx < 3; ++dx)
#pragma unroll
      for (int dy = 0; dy < 3; ++dy) {
        const float* row = &vb[((x + dx) * 18 + (y + dy)) * 20 + z0];
        float wv[12];
        *(float4*)&wv[0] = *(const float4*)&row[0];
        *(float4*)&wv[4] = *(const float4*)&row[4];
        *(float4*)&wv[8] = *(const float4*)&row[8];
        const float k0 = W2[(dx * 3 + dy) * 3 + 0];
        const float k1 = W2[(dx * 3 + dy) * 3 + 1];
        const float k2 = W2[(dx * 3 + dy) * 3 + 2];
#pragma unroll
        for (int z = 0; z < 8; ++z)
          acc[z] = fmaf(k0, wv[z], fmaf(k1, wv[z + 1], fmaf(k2, wv[z + 2], acc[z])));
      }
    const int vbase = (x * 16 + y) * 16 + z0;
#pragma unroll
    for (int z = 0; z < 8; ++z) {
      float tt = acc[z] * s2 + d2;
      vls[vbase + z] = tt > 0.f ? tt : 0.1f * tt;
    }
  }
  __syncthreads();

  const uint2* __restrict__ dv2 = (const uint2*)(dvt + (size_t)b * N_ * 2);
  float* __restrict__ orow = out + ((size_t)(b * C_ + c)) * N_;
#pragma unroll 4
  for (int i = 0; i < 16; ++i) {
    const int n = t + i * 1024;
    uint2 r = dv2[n];
    float o = orow[n];
    const int base = (int)(r.x & 0xffffu);
    const float fz = bfhi(r.x);
    const float fx = bflo(r.y), fy = bfhi(r.y);
    const float* v0 = &vls[base];
    float a0 = v0[0],   a1 = v0[1];
    float b0 = v0[16],  b1 = v0[17];
    float c0 = v0[256], c1 = v0[257];
    float d0 = v0[272], d1 = v0[273];
    float zA = fmaf(fz, a1 - a0, a0);
    float zB = fmaf(fz, b1 - b0, b0);
    float zC = fmaf(fz, c1 - c0, c0);
    float zD = fmaf(fz, d1 - d0, d0);
    float yAB = fmaf(fy, zB - zA, zA);
    float yCD = fmaf(fy, zD - zC, zC);
    orow[n] = o + fmaf(fx, yCD - yAB, yAB);
  }
}

// ---------------------------------------------------------------------------
extern "C" void kernel_launch(void* const* d_in, const int* in_sizes, int n_in,
                              void* d_out, int out_size, void* d_ws, size_t ws_size,
                              hipStream_t stream) {
  const float* x     = (const float*)d_in[0];
  const float* xyz   = (const float*)d_in[1];
  const int*   idx   = (const int*)  d_in[2];
  const float* w3d1  = (const float*)d_in[3];
  const float* b3d1  = (const float*)d_in[4];
  const float* bn3d1 = (const float*)d_in[5];
  const float* w3d2  = (const float*)d_in[6];
  const float* b3d2  = (const float*)d_in[7];
  const float* bn3d2 = (const float*)d_in[8];
  const float* pw1   = (const float*)d_in[9];
  const float* pbn   = (const float*)d_in[10];
  const float* pw2   = (const float*)d_in[11];
  const float* ptbn  = (const float*)d_in[12];
  float* out = (float*)d_out;
  float* ws  = (float*)d_ws;

  k_init<<<dim3(12 + FILL_BLOCKS), dim3(256), 0, stream>>>(
      xyz, ws + OFF_MEANS, ws + OFF_SUMS);
  k_prep<<<dim3(B_ * N_ / 64), dim3(256), 0, stream>>>(
      x, xyz, pw1, ws + OFF_MEANS, ptbn,
      (unsigned short*)(ws + OFF_XT), ws + OFF_PTS,
      (unsigned*)(ws + OFF_PTSH), (unsigned*)(ws + OFF_DVT),
      ws + OFF_SUMS, ws + OFF_CNTS);
  k_pt_tr<<<dim3(B_ * N_ / 32 + B_ * 64), dim3(256), 0, stream>>>(
      (const unsigned short*)(ws + OFF_XT), ws + OFF_PTS,
      (const unsigned*)(ws + OFF_PTSH), idx, pbn, pw2, ptbn, out,
      ws + OFF_SUMS, ws + OFF_CNTS, (unsigned*)(ws + OFF_VT16));
  k_convdevox<<<dim3(B_ * C_), dim3(1024), 0, stream>>>(
      (const unsigned*)(ws + OFF_VT16), w3d1, b3d1, bn3d1, w3d2, b3d2, bn3d2,
      (const unsigned*)(ws + OFF_DVT), out);
}